// Round 10
// baseline (51.958 us; speedup 1.0000x reference)
//
#include <hip/hip_runtime.h>
#include <hip/hip_bf16.h>

#define H 1024
#define MAXLEN 512

typedef __bf16 bf16x8 __attribute__((ext_vector_type(8)));
typedef __bf16 bf16x4 __attribute__((ext_vector_type(4)));
typedef float  f32x4  __attribute__((ext_vector_type(4)));

__device__ __forceinline__ float wave_reduce_sum(float a) {
    #pragma unroll
    for (int off = 32; off; off >>= 1) a += __shfl_xor(a, off);
    return a;
}
__device__ __forceinline__ float wave_reduce_max(float a) {
    #pragma unroll
    for (int off = 32; off; off >>= 1) a = fmaxf(a, __shfl_xor(a, off));
    return a;
}
__device__ __forceinline__ float cohLoad(const float* p) {
    return __hip_atomic_load(p, __ATOMIC_RELAXED, __HIP_MEMORY_SCOPE_AGENT);
}

// ws float layout:
//   logits[512] @0 | y1[1024] @512 | counters @1536 (9 x 64B lines)
//   Gt0 @4096 | Gt1 @4096+512K | gi_pad[3072][16] @WS_GI
#define WS_LOGITS 0
#define WS_Y1     512
#define WS_CNT    1536
#define WS_GT     4096
#define GT_HALF   (1024 * 512)
#define WS_GI     (WS_GT + 2 * GT_HALF)
#define WS_FLOATS (WS_GI + 3072 * 16)

// ================= Node 1: Gt = W2 @ enc^T (split-K, XCD-grouped) || logits || y1 + zero(gi)
__global__ __launch_bounds__(512)
void node1(const int* __restrict__ inputId,
           const float* __restrict__ hidden,
           const float* __restrict__ enc,
           const float* __restrict__ embed_table,
           const float* __restrict__ attn_w,
           const float* __restrict__ attn_b,
           const float* __restrict__ comb_w,
           const float* __restrict__ comb_b,
           float* __restrict__ ws) {
    float* logits = ws + WS_LOGITS;
    float* y1     = ws + WS_Y1;

    __shared__ __bf16 Asm[2][128][64];
    __shared__ __bf16 Bsm[2][64][64];

    const int tid  = threadIdx.x;
    const int lane = tid & 63;
    const int w    = tid >> 6;
    const int b    = blockIdx.x;

    if (b < 128) {
        const int pBase = (b & 7) * 128;          // p == b%8 == XCD under round-robin
        const int qBase = ((b >> 3) & 7) * 64;
        const int kh    = b >> 6;
        const int kBase = kh * 512;
        float* GtH = ws + WS_GT + (size_t)kh * GT_HALF;

        const int wp = w >> 1;
        const int wq = w & 1;
        const int row16 = tid >> 4, c4 = tid & 15;

        f32x4 acc[2][2];
        #pragma unroll
        for (int m = 0; m < 2; ++m)
            #pragma unroll
            for (int n = 0; n < 2; ++n) acc[m][n] = (f32x4){0.f, 0.f, 0.f, 0.f};

        float4 ra[4], rb[2];
        auto loadChunk = [&](int c) {
            const int k0 = kBase + c * 64;
            #pragma unroll
            for (int i = 0; i < 4; ++i)
                ra[i] = *(const float4*)(comb_w + (size_t)(pBase + row16 + i * 32) * 2048 + 1024 + k0 + c4 * 4);
            #pragma unroll
            for (int i = 0; i < 2; ++i)
                rb[i] = *(const float4*)(enc + (size_t)(qBase + row16 + i * 32) * 1024 + k0 + c4 * 4);
        };
        auto writeChunk = [&](int buf) {
            #pragma unroll
            for (int i = 0; i < 4; ++i) {
                int row = row16 + i * 32;
                int off = ((((c4 >> 1) ^ (row & 7)) << 4) | ((c4 & 1) << 3));
                bf16x4 v;
                v[0] = (__bf16)ra[i].x; v[1] = (__bf16)ra[i].y;
                v[2] = (__bf16)ra[i].z; v[3] = (__bf16)ra[i].w;
                *(bf16x4*)((char*)(&Asm[buf][row][0]) + off) = v;
            }
            #pragma unroll
            for (int i = 0; i < 2; ++i) {
                int row = row16 + i * 32;
                int off = ((((c4 >> 1) ^ (row & 7)) << 4) | ((c4 & 1) << 3));
                bf16x4 v;
                v[0] = (__bf16)rb[i].x; v[1] = (__bf16)rb[i].y;
                v[2] = (__bf16)rb[i].z; v[3] = (__bf16)rb[i].w;
                *(bf16x4*)((char*)(&Bsm[buf][row][0]) + off) = v;
            }
        };

        loadChunk(0);
        writeChunk(0);
        __syncthreads();

        for (int c = 0; c < 8; ++c) {
            const int cur = c & 1;
            if (c < 7) loadChunk(c + 1);
            #pragma unroll
            for (int ks = 0; ks < 2; ++ks) {
                const int slot = ks * 4 + (lane >> 4);
                bf16x8 af[2], bfv[2];
                #pragma unroll
                for (int m = 0; m < 2; ++m) {
                    int row = wp * 32 + m * 16 + (lane & 15);
                    af[m] = *(const bf16x8*)((const char*)(&Asm[cur][row][0]) + ((slot ^ (row & 7)) << 4));
                }
                #pragma unroll
                for (int n = 0; n < 2; ++n) {
                    int row = wq * 32 + n * 16 + (lane & 15);
                    bfv[n] = *(const bf16x8*)((const char*)(&Bsm[cur][row][0]) + ((slot ^ (row & 7)) << 4));
                }
                #pragma unroll
                for (int m = 0; m < 2; ++m)
                    #pragma unroll
                    for (int n = 0; n < 2; ++n)
                        acc[m][n] = __builtin_amdgcn_mfma_f32_16x16x32_bf16(af[m], bfv[n], acc[m][n], 0, 0, 0);
            }
            if (c < 7) writeChunk(cur ^ 1);
            __syncthreads();
        }

        #pragma unroll
        for (int m = 0; m < 2; ++m) {
            int p0 = pBase + wp * 32 + m * 16 + (lane >> 4) * 4;
            #pragma unroll
            for (int n = 0; n < 2; ++n) {
                int q = qBase + wq * 32 + n * 16 + (lane & 15);
                #pragma unroll
                for (int i = 0; i < 4; ++i)
                    GtH[(size_t)(p0 + i) * 512 + q] = acc[m][n][i];
            }
        }
    } else if (b < 192) {
        const float* embed = embed_table + (size_t)inputId[0] * H;
        int row = (b - 128) * 8 + w;
        const float* wrow = attn_w + (size_t)row * (2 * H);
        float acc = 0.f;
        #pragma unroll
        for (int it = 0; it < 8; ++it) {
            int base = it * 256 + lane * 4;
            float4 wv = *(const float4*)(wrow + base);
            float4 cv = (it < 4) ? *(const float4*)(embed + base)
                                 : *(const float4*)(hidden + (base - H));
            acc += wv.x * cv.x + wv.y * cv.y + wv.z * cv.z + wv.w * cv.w;
        }
        acc = wave_reduce_sum(acc);
        if (lane == 0) logits[row] = acc + attn_b[row];
    } else {
        const float* embed = embed_table + (size_t)inputId[0] * H;
        #pragma unroll
        for (int rr = 0; rr < 2; ++rr) {
            int row = (b - 192) * 16 + w * 2 + rr;
            const float* wrow = comb_w + (size_t)row * (2 * H);
            float acc = 0.f;
            #pragma unroll
            for (int it = 0; it < 4; ++it) {
                int base = it * 256 + lane * 4;
                float4 wv = *(const float4*)(wrow + base);
                float4 evv = *(const float4*)(embed + base);
                acc += wv.x * evv.x + wv.y * evv.y + wv.z * evv.z + wv.w * evv.w;
            }
            acc = wave_reduce_sum(acc);
            if (lane == 0) y1[row] = acc + comb_b[row];
        }
        // zero gi_pad (blocks 192..199) + counters (block 192).
        // Plain stores: kernel-end L2 writeback makes them visible to node2's
        // L3 atomics (same contract the Gt handoff relies on — proven R7-R9).
        if (b < 200) {
            float* gi = ws + WS_GI;
            int bz = b - 192;
            #pragma unroll
            for (int q = 0; q < 12; ++q)
                gi[bz * 6144 + q * 512 + tid] = 0.f;
            if (b == 192 && tid < 9)
                *(unsigned*)(ws + WS_CNT + tid * 16) = 0u;
        }
    }
}

// ================= Node 2: softmax + x + GRU-partials (atomics) + last-block finish
// 128 blocks x 512: g = b>>6 (j-half), b16 = b&63 (x rows / k-slice [b16*16, +16)).
__global__ __launch_bounds__(512)
void node2(const float* __restrict__ w_ih,
           const float* __restrict__ b_ih,
           const float* __restrict__ b_hh,
           float* __restrict__ ws,
           float* __restrict__ d_out) {
    const float* logits = ws + WS_LOGITS;
    const float* y1     = ws + WS_Y1;
    const float* Gt0    = ws + WS_GT;
    const float* Gt1    = ws + WS_GT + GT_HALF;
    float* gi = ws + WS_GI;
    unsigned* cnt = (unsigned*)(ws + WS_CNT);

    __shared__ float wsm[MAXLEN];
    __shared__ float redm[8], reds[8];
    __shared__ float x_lds[16];
    __shared__ int lastFlag;

    const int tid = threadIdx.x, lane = tid & 63, w = tid >> 6;
    const int b = blockIdx.x;
    const int g = b >> 6, b16 = b & 63;

    // ---- softmax (redundant per block; NT == MAXLEN) ----
    float l = logits[tid];
    float m = wave_reduce_max(l);
    if (lane == 0) redm[w] = m;
    __syncthreads();
    m = redm[0];
    #pragma unroll
    for (int i = 1; i < 8; ++i) m = fmaxf(m, redm[i]);
    float e = expf(l - m);
    float s = wave_reduce_sum(e);
    if (lane == 0) reds[w] = s;
    __syncthreads();
    s = 0.f;
    #pragma unroll
    for (int i = 0; i < 8; ++i) s += reds[i];
    float wgt = e / s;
    wsm[tid] = wgt;
    if (b == 0) d_out[2048 + tid] = wgt;     // attnWeights (exact fp32)
    __syncthreads();

    // ---- x rows [b16*16, +16): 2 per wave ----
    #pragma unroll
    for (int rr = 0; rr < 2; ++rr) {
        int r = b16 * 16 + w * 2 + rr;
        const float* g0 = Gt0 + (size_t)r * 512;
        const float* g1 = Gt1 + (size_t)r * 512;
        float acc = 0.f;
        #pragma unroll
        for (int i = 0; i < 8; ++i) {
            int k = lane + 64 * i;
            acc += (g0[k] + g1[k]) * wsm[k];
        }
        acc = wave_reduce_sum(acc);
        if (lane == 0) x_lds[w * 2 + rr] = fmaxf(y1[r] + acc, 0.f);
    }
    __syncthreads();

    float xr[16];
    #pragma unroll
    for (int kk = 0; kk < 16; ++kk) xr[kk] = x_lds[kk];

    // ---- GRU partials: j in [g*1536, +1536), k-slice = [b16*16, +16) (one 64B line/row) ----
    const int k0 = b16 * 16;
    #pragma unroll
    for (int ii = 0; ii < 3; ++ii) {
        int j = g * 1536 + ii * 512 + tid;
        const float* wr = w_ih + (size_t)j * H + k0;
        float4 a0 = *(const float4*)(wr);
        float4 a1 = *(const float4*)(wr + 4);
        float4 a2 = *(const float4*)(wr + 8);
        float4 a3 = *(const float4*)(wr + 12);
        float acc = a0.x * xr[0]  + a0.y * xr[1]  + a0.z * xr[2]  + a0.w * xr[3]
                  + a1.x * xr[4]  + a1.y * xr[5]  + a1.z * xr[6]  + a1.w * xr[7]
                  + a2.x * xr[8]  + a2.y * xr[9]  + a2.z * xr[10] + a2.w * xr[11]
                  + a3.x * xr[12] + a3.y * xr[13] + a3.z * xr[14] + a3.w * xr[15];
        atomicAdd(gi + (size_t)j * 16, acc);   // 64B-padded: <=64 adds/line, fire-and-forget
    }

    // ---- completion: two-level counters (16 RMWs/line, NO polling) ----
    __builtin_amdgcn_fence(__ATOMIC_RELEASE, "agent");
    if (tid == 0) {
        lastFlag = 0;
        unsigned o = __hip_atomic_fetch_add(cnt + (b >> 4) * 16, 1u,
                                            __ATOMIC_ACQ_REL, __HIP_MEMORY_SCOPE_AGENT);
        if (o == 15u) {
            unsigned r2 = __hip_atomic_fetch_add(cnt + 128, 1u,
                                                 __ATOMIC_ACQ_REL, __HIP_MEMORY_SCOPE_AGENT);
            if (r2 == 7u) lastFlag = 1;        // globally last block
        }
    }
    __syncthreads();

    if (lastFlag) {
        __builtin_amdgcn_fence(__ATOMIC_ACQUIRE, "agent");
        for (int jj = tid; jj < 1024; jj += 512) {
            float gr = cohLoad(gi + (size_t)jj * 16);
            float gz = cohLoad(gi + (size_t)(1024 + jj) * 16);
            float gn = cohLoad(gi + (size_t)(2048 + jj) * 16);
            float gi_r = gr + b_ih[jj];
            float gi_z = gz + b_ih[1024 + jj];
            float gi_n = gn + b_ih[2048 + jj];
            float r = 1.f / (1.f + expf(-(gi_r + b_hh[jj])));
            float z = 1.f / (1.f + expf(-(gi_z + b_hh[1024 + jj])));
            float n = tanhf(gi_n + r * b_hh[2048 + jj]);
            float hnew = (1.f - z) * n;        // + z*h0, h0 = 0
            float outv = 1.f / (1.f + expf(-hnew));
            d_out[jj] = outv;
            d_out[1024 + jj] = hnew;
        }
    }
}

// ================= Fallback (R2-proven 4-kernel path, used if ws too small) =================
__global__ void fb_kA(const int* __restrict__ inputId, const float* __restrict__ embed_table,
                      const float* __restrict__ hidden, const float* __restrict__ attn_w,
                      const float* __restrict__ attn_b, float* __restrict__ logits) {
    int lane = threadIdx.x & 63;
    int row = blockIdx.x * 4 + (threadIdx.x >> 6);
    const float* embed = embed_table + (size_t)inputId[0] * H;
    const float* wrow = attn_w + (size_t)row * (2 * H);
    float acc = 0.f;
    #pragma unroll
    for (int it = 0; it < 8; ++it) {
        int base = it * 256 + lane * 4;
        float4 wv = *(const float4*)(wrow + base);
        float4 cv = (it < 4) ? *(const float4*)(embed + base)
                             : *(const float4*)(hidden + (base - H));
        acc += wv.x * cv.x + wv.y * cv.y + wv.z * cv.z + wv.w * cv.w;
    }
    acc = wave_reduce_sum(acc);
    if (lane == 0) logits[row] = acc + attn_b[row];
}
__global__ void fb_kB(const float* __restrict__ logits, const float* __restrict__ enc,
                      float* __restrict__ attnApplied, float* __restrict__ out_w) {
    __shared__ float w_lds[MAXLEN];
    __shared__ float red[4];
    __shared__ float part[8][32];
    int tid = threadIdx.x, lane = tid & 63, wid = tid >> 6;
    float l0 = logits[tid], l1 = logits[tid + 256];
    float m = wave_reduce_max(fmaxf(l0, l1));
    if (lane == 0) red[wid] = m;
    __syncthreads();
    m = fmaxf(fmaxf(red[0], red[1]), fmaxf(red[2], red[3]));
    __syncthreads();
    float e0 = expf(l0 - m), e1 = expf(l1 - m);
    float s = wave_reduce_sum(e0 + e1);
    if (lane == 0) red[wid] = s;
    __syncthreads();
    s = red[0] + red[1] + red[2] + red[3];
    float inv = 1.f / s;
    float w0 = e0 * inv, w1 = e1 * inv;
    w_lds[tid] = w0; w_lds[tid + 256] = w1;
    if (blockIdx.x == 0) { out_w[tid] = w0; out_w[tid + 256] = w1; }
    __syncthreads();
    int c = tid & 31, ks = tid >> 5;
    int col = blockIdx.x * 32 + c;
    float acc = 0.f;
    for (int k = ks; k < MAXLEN; k += 8) acc += w_lds[k] * enc[(size_t)k * H + col];
    part[ks][c] = acc;
    __syncthreads();
    if (tid < 32) {
        float t = 0.f;
        #pragma unroll
        for (int i = 0; i < 8; ++i) t += part[i][tid];
        attnApplied[blockIdx.x * 32 + tid] = t;
    }
}
__global__ void fb_kC(const int* __restrict__ inputId, const float* __restrict__ embed_table,
                      const float* __restrict__ attnApplied, const float* __restrict__ comb_w,
                      const float* __restrict__ comb_b, float* __restrict__ x) {
    int lane = threadIdx.x & 63;
    int row = blockIdx.x * 4 + (threadIdx.x >> 6);
    const float* embed = embed_table + (size_t)inputId[0] * H;
    const float* wrow = comb_w + (size_t)row * (2 * H);
    float acc = 0.f;
    #pragma unroll
    for (int it = 0; it < 8; ++it) {
        int base = it * 256 + lane * 4;
        float4 wv = *(const float4*)(wrow + base);
        float4 cv = (it < 4) ? *(const float4*)(embed + base)
                             : *(const float4*)(attnApplied + (base - H));
        acc += wv.x * cv.x + wv.y * cv.y + wv.z * cv.z + wv.w * cv.w;
    }
    acc = wave_reduce_sum(acc);
    if (lane == 0) x[row] = fmaxf(acc + comb_b[row], 0.f);
}
__global__ void fb_kD(const float* __restrict__ w_ih, const float* __restrict__ b_ih,
                      const float* __restrict__ b_hh, const float* __restrict__ x,
                      float* __restrict__ d_out) {
    int lane = threadIdx.x & 63;
    int j = blockIdx.x * 4 + (threadIdx.x >> 6);
    float acc0 = 0.f, acc1 = 0.f, acc2 = 0.f;
    const float* wr = w_ih + (size_t)j * H;
    const float* wz = w_ih + (size_t)(H + j) * H;
    const float* wn = w_ih + (size_t)(2 * H + j) * H;
    #pragma unroll
    for (int it = 0; it < 4; ++it) {
        int base = it * 256 + lane * 4;
        float4 xv = *(const float4*)(x + base);
        float4 a = *(const float4*)(wr + base);
        float4 c = *(const float4*)(wz + base);
        float4 d = *(const float4*)(wn + base);
        acc0 += a.x * xv.x + a.y * xv.y + a.z * xv.z + a.w * xv.w;
        acc1 += c.x * xv.x + c.y * xv.y + c.z * xv.z + c.w * xv.w;
        acc2 += d.x * xv.x + d.y * xv.y + d.z * xv.z + d.w * xv.w;
    }
    #pragma unroll
    for (int off = 32; off; off >>= 1) {
        acc0 += __shfl_xor(acc0, off);
        acc1 += __shfl_xor(acc1, off);
        acc2 += __shfl_xor(acc2, off);
    }
    if (lane == 0) {
        float gi_r = acc0 + b_ih[j];
        float gi_z = acc1 + b_ih[H + j];
        float gi_n = acc2 + b_ih[2 * H + j];
        float r = 1.f / (1.f + expf(-(gi_r + b_hh[j])));
        float z = 1.f / (1.f + expf(-(gi_z + b_hh[H + j])));
        float n = tanhf(gi_n + r * b_hh[2 * H + j]);
        float hnew = (1.f - z) * n;
        float outv = 1.f / (1.f + expf(-hnew));
        d_out[j] = outv;
        d_out[H + j] = hnew;
    }
}

extern "C" void kernel_launch(void* const* d_in, const int* in_sizes, int n_in,
                              void* d_out, int out_size, void* d_ws, size_t ws_size,
                              hipStream_t stream) {
    const int*   inputId     = (const int*)d_in[0];
    const float* hidden      = (const float*)d_in[1];
    const float* enc         = (const float*)d_in[2];
    const float* embed_table = (const float*)d_in[3];
    const float* attn_w      = (const float*)d_in[4];
    const float* attn_b      = (const float*)d_in[5];
    const float* comb_w      = (const float*)d_in[6];
    const float* comb_b      = (const float*)d_in[7];
    const float* w_ih        = (const float*)d_in[8];
    // d_in[9] = w_hh dead: h0 == 0 -> gh = b_hh
    const float* b_ih        = (const float*)d_in[10];
    const float* b_hh        = (const float*)d_in[11];

    float* out = (float*)d_out;   // [0:1024) out, [1024:2048) h_new, [2048:2560) attnWeights
    float* ws  = (float*)d_ws;

    if (ws_size >= (size_t)WS_FLOATS * sizeof(float)) {
        node1<<<256, 512, 0, stream>>>(inputId, hidden, enc, embed_table,
                                       attn_w, attn_b, comb_w, comb_b, ws);
        node2<<<128, 512, 0, stream>>>(w_ih, b_ih, b_hh, ws, out);
    } else {
        float* logits      = ws;
        float* attnApplied = ws + 512;
        float* x           = ws + 2048;
        fb_kA<<<128, 256, 0, stream>>>(inputId, embed_table, hidden, attn_w, attn_b, logits);
        fb_kB<<<32,  256, 0, stream>>>(logits, enc, attnApplied, out + 2048);
        fb_kC<<<256, 256, 0, stream>>>(inputId, embed_table, attnApplied, comb_w, comb_b, x);
        fb_kD<<<256, 256, 0, stream>>>(w_ih, b_ih, b_hh, x, out);
    }
}